// Round 13
// baseline (14858.255 us; speedup 1.0000x reference)
//
#include <hip/hip_runtime.h>

// RNN echo-state scan on MI355X — round 13.
// Protocol = proven (r2/r6/r9/r12): sc1 write-through publish -> vmcnt(0)
// drain -> agent-atomic counter post; consumer atomic poll -> acquire-fence
// (buffer_inv) -> plain batched loads.
// New vs r12 (perf only):
//  * fully symmetric waves: each wave polls (lane0) + fences + posts itself;
//    ZERO per-step __syncthreads/s_barrier.
//  * x/noise issued as asm loads BEFORE the poll (read-only => fence-free),
//    consumed after the GEMM; post-fence vmcnt(0) makes WAITV(24/16/8/0)
//    count the 32 A-loads exactly.
//  * W split: even K-chunks + x chunks in REGISTERS (144 VGPR/lane, loaded
//    once); odd chunks in LDS (64KB). W-LDS reads halve (68 -> 34 b128/wave).
//  * x single-plane f16 (drops 4 MFMAs + split VALU).

#define TT    2048
#define BB    64
#define NIN   64
#define NRECN 1024
#define NGRP  8
#define WPGRP 16
#define NWG   128
#define NOISE_STD 0.001f

typedef __attribute__((ext_vector_type(8))) _Float16 half8;
typedef __attribute__((ext_vector_type(4))) float f32x4;
typedef __attribute__((ext_vector_type(2))) unsigned int u32x2;

__device__ __forceinline__ void st_d2_sc1(void* p, u32x2 w) {
  asm volatile("global_store_dwordx2 %0, %1, off sc1" :: "v"(p), "v"(w) : "memory");
}
__device__ __forceinline__ unsigned pk2h(float a, float b) {
  unsigned short ua = __builtin_bit_cast(unsigned short, (_Float16)a);
  unsigned short ub = __builtin_bit_cast(unsigned short, (_Float16)b);
  return (unsigned)ua | ((unsigned)ub << 16);
}
__device__ __forceinline__ half8 cvt8(const f32x4& a, const f32x4& b) {
  half8 r;
  #pragma unroll
  for (int j = 0; j < 4; ++j) { r[j] = (_Float16)a[j]; r[4+j] = (_Float16)b[j]; }
  return r;
}

// ordered asm 16B loads (so vmcnt accounting is exact)
#define LDA16(V, P, OFF) \
  asm volatile("global_load_dwordx4 %0, %1, off offset:%c2" \
               : "=&v"(V) : "v"(P), "n"(OFF))
#define WAITV(N) asm volatile("s_waitcnt vmcnt(" #N ")" ::: "memory")
#define SB0 __builtin_amdgcn_sched_barrier(0)
#define MFMA16 __builtin_amdgcn_mfma_f32_16x16x32_f16

__global__ __launch_bounds__(128, 1) void rnn_scan_kernel(
    const float* __restrict__ x, const float* __restrict__ W_ih,
    const float* __restrict__ W_hh, const float* __restrict__ noise,
    float* __restrict__ out, int* __restrict__ flags,
    _Float16* __restrict__ th)
{
  extern __shared__ _Float16 smem[];   // ODD W chunks: [16oc][4][64col][8] f16

  const int wg = blockIdx.x, grp = wg & 7, gidx = wg >> 3;
  const int tid = threadIdx.x, lane = tid & 63, wv = tid >> 6;
  const int l15 = lane & 15, g4 = lane >> 4;

  // one-time: odd recurrent W chunks -> LDS (32768 elements = 64KB)
  for (int idx = tid; idx < 64 * 512; idx += 128) {
    int col = idx >> 9, kk = idx & 511;
    int oc = kk >> 5, g = (kk >> 3) & 3, j = kk & 7;
    int k = (2 * oc + 1) * 32 + g * 8 + j;          // odd chunk k in [32,1024)
    smem[(oc * 4 + g) * 512 + col * 8 + j] =
        (_Float16)W_hh[(size_t)(gidx * 64 + col) * NRECN + k];
  }

  // one-time: even recurrent chunks (c=0,2,..30) + x chunks (c=32,33) -> REGS
  half8 Wr[36];
  #pragma unroll
  for (int e = 0; e < 16; ++e) {
    const int k0 = (2 * e) * 32 + g4 * 8;
    #pragma unroll
    for (int tl = 0; tl < 2; ++tl) {
      const int n = gidx * 64 + wv * 32 + tl * 16 + l15;
      const float* wp = W_hh + (size_t)n * NRECN + k0;
      Wr[e * 2 + tl] = cvt8(*(const f32x4*)wp, *(const f32x4*)(wp + 4));
    }
  }
  #pragma unroll
  for (int cx = 0; cx < 2; ++cx) {
    const int k0 = cx * 32 + g4 * 8;
    #pragma unroll
    for (int tl = 0; tl < 2; ++tl) {
      const int n = gidx * 64 + wv * 32 + tl * 16 + l15;
      const float* wp = W_ih + (size_t)n * NIN + k0;
      Wr[32 + cx * 2 + tl] = cvt8(*(const f32x4*)wp, *(const f32x4*)(wp + 4));
    }
  }
  __syncthreads();

  int* ctr = flags + grp * 16;                  // one counter/group (64B line)
  _Float16* thg = th + grp * (2 * 8 * 1024);    // [buf][8 batch][1024] f16
  const int b_eff = grp * 8 + (l15 & 7);
  const float* xrow = x + (size_t)b_eff * TT * NIN;
  const int cB = gidx * 64 + wv * 32 + g4 * 4;  // lane's 4-col base (tile0)
  const _Float16* wlp = smem + g4 * 512 + (wv * 32 + l15) * 8;  // +oc*2048

  for (int t = 0; t < TT; ++t) {
    // ---- issue x/noise asm loads FIRST (read-only: fence-independent)
    f32x4 v0, v1, v2, v3, n0, n1;
    const float* xp = xrow + (size_t)t * NIN + g4 * 8;
    const float* np = noise + (size_t)t * NRECN + cB;
    LDA16(v0, xp, 0);  LDA16(v1, xp, 16);
    LDA16(v2, xp, 128); LDA16(v3, xp, 144);
    LDA16(n0, np, 0);  LDA16(n1, np, 64);

    f32x4 P0{0,0,0,0}, P1{0,0,0,0}, Q0{0,0,0,0}, Q1{0,0,0,0};

    if (t > 0) {
      // ---- proven consume protocol, per-wave
      const int target = t * 32;                 // 32 wave-posts/group/step
      if (lane == 0) {
        while (__hip_atomic_load(ctr, __ATOMIC_RELAXED,
                                 __HIP_MEMORY_SCOPE_AGENT) < target) { }
      }
      __builtin_amdgcn_fence(__ATOMIC_ACQUIRE, "agent");   // buffer_inv
      asm volatile("s_waitcnt vmcnt(0) lgkmcnt(0)" ::: "memory"); // clean slate
      SB0;

      // ---- batched A loads: exactly 32 outstanding -> counted consume
      const _Float16* abase =
          thg + (t & 1) * 8192 + (l15 & 7) * 1024 + g4 * 8;
      half8 A[32];
      #pragma unroll
      for (int c = 0; c < 32; ++c) LDA16(A[c], abase, c * 64);

      #pragma unroll
      for (int blk = 0; blk < 4; ++blk) {
        if (blk == 0) { WAITV(24); } else if (blk == 1) { WAITV(16); }
        else if (blk == 2) { WAITV(8); } else { WAITV(0); }
        SB0;
        #pragma unroll
        for (int c = blk * 8; c < blk * 8 + 8; ++c) {
          if ((c & 1) == 0) {                    // even chunk: W from regs
            P0 = MFMA16(Wr[(c >> 1) * 2 + 0], A[c], P0, 0, 0, 0);
            P1 = MFMA16(Wr[(c >> 1) * 2 + 1], A[c], P1, 0, 0, 0);
          } else {                               // odd chunk: W from LDS
            const int oc = c >> 1;
            half8 b0 = *(const half8*)(wlp + oc * 2048);
            half8 b1 = *(const half8*)(wlp + oc * 2048 + 128);
            Q0 = MFMA16(b0, A[c], Q0, 0, 0, 0);
            Q1 = MFMA16(b1, A[c], Q1, 0, 0, 0);
          }
        }
      }
    } else {
      WAITV(0);                                  // x/noise ready at t=0
    }

    // ---- x part (single-plane f16; W from regs)
    {
      half8 xh0 = cvt8(v0, v1), xh1 = cvt8(v2, v3);
      P0 = MFMA16(Wr[32], xh0, P0, 0, 0, 0);
      P1 = MFMA16(Wr[33], xh0, P1, 0, 0, 0);
      P0 = MFMA16(Wr[34], xh1, P0, 0, 0, 0);
      P1 = MFMA16(Wr[35], xh1, P1, 0, 0, 0);
    }

    // ---- epilogue: h, tanh, coalesced sc1 publish, per-wave post
    f32x4 h0, h1;
    #pragma unroll
    for (int r = 0; r < 4; ++r) {
      h0[r] = P0[r] + Q0[r] + n0[r] * NOISE_STD;
      h1[r] = P1[r] + Q1[r] + n1[r] * NOISE_STD;
    }
    _Float16* ob = thg + ((t + 1) & 1) * 8192;
    float tv0[4], tv1[4];
    #pragma unroll
    for (int r = 0; r < 4; ++r) {
      tv0[r] = 1.f - 2.f / (__expf(2.f * h0[r]) + 1.f);
      tv1[r] = 1.f - 2.f / (__expf(2.f * h1[r]) + 1.f);
    }
    if (l15 < 8) {                               // lanes 8..15 = dup batches
      u32x2 w0, w1;
      w0[0] = pk2h(tv0[0], tv0[1]); w0[1] = pk2h(tv0[2], tv0[3]);
      w1[0] = pk2h(tv1[0], tv1[1]); w1[1] = pk2h(tv1[2], tv1[3]);
      st_d2_sc1(ob + l15 * 1024 + cB, w0);
      st_d2_sc1(ob + l15 * 1024 + cB + 16, w1);
    }
    WAITV(0);                                    // my th stores committed
    if (lane == 0)
      __hip_atomic_fetch_add(ctr, 1, __ATOMIC_RELAXED,
                             __HIP_MEMORY_SCOPE_AGENT);

    // ---- outputs, off the critical path (drained by next step's waitcnt)
    if (grp == 7 && l15 == 7) {                  // batch 63 row
      #pragma unroll
      for (int r = 0; r < 4; ++r) {
        out[(size_t)(cB + r) * TT + t] = h0[r];
        out[(size_t)(cB + 16 + r) * TT + t] = h1[r];
      }
    }
    if (t == TT - 1 && l15 < 8) {                // final h, coalesced
      const int br = grp * 8 + l15;
      *(f32x4*)(out + (size_t)NRECN * TT + (size_t)br * NRECN + cB) = h0;
      *(f32x4*)(out + (size_t)NRECN * TT + (size_t)br * NRECN + cB + 16) = h1;
    }
  }
}

extern "C" void kernel_launch(void* const* d_in, const int* in_sizes, int n_in,
                              void* d_out, int out_size, void* d_ws, size_t ws_size,
                              hipStream_t stream) {
  const float* x     = (const float*)d_in[0];
  const float* W_ih  = (const float*)d_in[1];
  const float* W_hh  = (const float*)d_in[2];
  const float* noise = (const float*)d_in[3];
  float* out = (float*)d_out;

  char* ws = (char*)d_ws;
  int* flags = (int*)ws;                         // 8 counters, 64B apart
  _Float16* th = (_Float16*)(ws + 4096);         // [8][2][8][1024] f16 = 256 KB
  // ws usage: 4096 + 262144 = 266,240 bytes. Every byte of each tile is
  // rewritten by its group before being read -> no th memset needed.

  (void)hipMemsetAsync(flags, 0, 4096, stream);  // deterministic replays

  const size_t lds_bytes = 64 * 512 * sizeof(_Float16);   // 65,536
  (void)hipFuncSetAttribute((const void*)rnn_scan_kernel,
                            hipFuncAttributeMaxDynamicSharedMemorySize,
                            (int)lds_bytes);

  rnn_scan_kernel<<<dim3(NWG), dim3(128), lds_bytes, stream>>>(
      x, W_ih, W_hh, noise, out, flags, th);
}

// Round 14
// 10101.711 us; speedup vs baseline: 1.4709x; 1.4709x over previous
//
#include <hip/hip_runtime.h>

// RNN echo-state scan on MI355X — round 14 = r12 skeleton + two fixes.
// Protocol (byte-identical to r12, proven): sc1 write-through publish ->
// vmcnt(0) drain -> syncthreads -> ONE agent-atomic post per WG; consumer
// tid0 poll -> wave0-elected acquire-fence -> syncthreads -> plain loads.
// Fix 1: x/noise for t+1 prefetched into REGS via asm loads issued at the end
//   of step t's GEMM -> their MALL miss hides under epilogue drain + poll;
//   x-MFMAs move AFTER the recurrent GEMM (off the pre-poll serial path).
// Fix 2: A-batch software-pipelined in 8-load blocks (<=24 in flight, 96
//   VGPR) -> no spill (r12's VGPR=112 proved the 32-load batch spilled).
// x single-plane f16 (r13 proved absmax 0.03125 unchanged).

#define TT    2048
#define BB    64
#define NIN   64
#define NRECN 1024
#define KTOT  1088
#define NGRP  8
#define WPGRP 16
#define NWG   128
#define NOISE_STD 0.001f

typedef __attribute__((ext_vector_type(8))) _Float16 half8;
typedef __attribute__((ext_vector_type(4))) float f32x4;
typedef __attribute__((ext_vector_type(2))) unsigned int u32x2;

__device__ __forceinline__ void st_d2_sc1(void* p, u32x2 w) {
  asm volatile("global_store_dwordx2 %0, %1, off sc1" :: "v"(p), "v"(w) : "memory");
}
__device__ __forceinline__ unsigned pk2h(float a, float b) {
  unsigned short ua = __builtin_bit_cast(unsigned short, (_Float16)a);
  unsigned short ub = __builtin_bit_cast(unsigned short, (_Float16)b);
  return (unsigned)ua | ((unsigned)ub << 16);
}
__device__ __forceinline__ half8 cvt8(const f32x4& a, const f32x4& b) {
  half8 r;
  #pragma unroll
  for (int j = 0; j < 4; ++j) { r[j] = (_Float16)a[j]; r[4+j] = (_Float16)b[j]; }
  return r;
}

#define LDA16(V, P, OFF) \
  asm volatile("global_load_dwordx4 %0, %1, off offset:%c2" \
               : "=&v"(V) : "v"(P), "n"(OFF))
#define WAITV(N) asm volatile("s_waitcnt vmcnt(" #N ")" ::: "memory")
#define SB0 __builtin_amdgcn_sched_barrier(0)
#define MFMA16 __builtin_amdgcn_mfma_f32_16x16x32_f16

// One K-chunk of the recurrent GEMM (W = A-operand from LDS, th = B-operand).
#define ACHUNK(c) {                                            \
    half8 b0 = *(const half8*)(whp0 + (c) * 2048);             \
    half8 b1 = *(const half8*)(whp1 + (c) * 2048);             \
    if ((c) & 1) {                                             \
      Q0 = MFMA16(b0, A[c], Q0, 0, 0, 0);                      \
      Q1 = MFMA16(b1, A[c], Q1, 0, 0, 0);                      \
    } else {                                                   \
      P0 = MFMA16(b0, A[c], P0, 0, 0, 0);                      \
      P1 = MFMA16(b1, A[c], P1, 0, 0, 0);                      \
    } }

__global__ __launch_bounds__(128, 1) void rnn_scan_kernel(
    const float* __restrict__ x, const float* __restrict__ W_ih,
    const float* __restrict__ W_hh, const float* __restrict__ noise,
    float* __restrict__ out, int* __restrict__ flags,
    _Float16* __restrict__ th)
{
  extern __shared__ _Float16 smem[];   // W f16, sub-chunk-major [136][64][8]

  const int wg = blockIdx.x, grp = wg & 7, gidx = wg >> 3;
  const int tid = threadIdx.x, lane = tid & 63, wv = tid >> 6;
  const int l15 = lane & 15, g4 = lane >> 4;

  // one-time: W slice (cols gidx*64..+64, K=1088) -> LDS f16 (r12 layout)
  for (int idx = tid; idx < 64 * KTOT; idx += 128) {
    int nr = idx / KTOT, k = idx - nr * KTOT;
    int ng = gidx * 64 + nr;
    float v = (k < NRECN) ? W_hh[(size_t)ng * NRECN + k]
                          : W_ih[(size_t)ng * NIN + (k - NRECN)];
    smem[(k >> 3) * 512 + nr * 8 + (k & 7)] = (_Float16)v;
  }
  __syncthreads();

  int* ctr = flags + grp * 16;                  // ONE counter per group
  const _Float16* whp0 = smem + g4 * 512 + (wv * 32 + l15) * 8; // +c*2048
  const _Float16* whp1 = whp0 + 128;
  _Float16* thg = th + grp * (2 * 8 * 1024);    // [buf][8 batch][1024] f16
  const int b_eff = grp * 8 + (l15 & 7);
  const float* xrow = x + (size_t)b_eff * TT * NIN;
  const int cB = gidx * 64 + wv * 32 + g4 * 4;  // lane's 4-col base (tile0)

  // prologue: x/noise for t=0 via plain loads (compiler-waited)
  f32x4 xv0, xv1, xv2, xv3, nv0, nv1;
  { const float* xp = xrow + g4 * 8;
    xv0 = *(const f32x4*)xp;        xv1 = *(const f32x4*)(xp + 4);
    xv2 = *(const f32x4*)(xp + 32); xv3 = *(const f32x4*)(xp + 36);
    nv0 = *(const f32x4*)(noise + cB);
    nv1 = *(const f32x4*)(noise + cB + 16); }

  for (int t = 0; t < TT; ++t) {
    f32x4 P0{0,0,0,0}, P1{0,0,0,0}, Q0{0,0,0,0}, Q1{0,0,0,0};

    if (t > 0) {
      // ---- proven consume protocol (r12): elected poll + fence, 1 barrier
      const int target = t * WPGRP;
      if (tid == 0) {
        while (__hip_atomic_load(ctr, __ATOMIC_RELAXED,
                                 __HIP_MEMORY_SCOPE_AGENT) < target) { }
      }
      if (wv == 0)
        __builtin_amdgcn_fence(__ATOMIC_ACQUIRE, "agent");  // one inv per WG
      __syncthreads();

      // ---- pipelined A-batch: 8-load blocks, <=24 outstanding (96 VGPR)
      const _Float16* abase =
          thg + (t & 1) * 8192 + (l15 & 7) * 1024 + g4 * 8;
      half8 A[32];
      #pragma unroll
      for (int c = 0; c < 8; ++c)  LDA16(A[c], abase, c * 64);        // B0
      #pragma unroll
      for (int c = 8; c < 16; ++c) LDA16(A[c], abase, c * 64);        // B1
      WAITV(8);  SB0;                                                 // B0 in
      #pragma unroll
      for (int c = 16; c < 24; ++c) LDA16(A[c], abase, c * 64);       // B2
      #pragma unroll
      for (int c = 0; c < 8; ++c)  ACHUNK(c);
      WAITV(8);  SB0;                                                 // B1 in
      #pragma unroll
      for (int c = 24; c < 32; ++c) LDA16(A[c], abase, c * 64);       // B3
      #pragma unroll
      for (int c = 8; c < 16; ++c) ACHUNK(c);
      WAITV(8);  SB0;                                                 // B2 in
      #pragma unroll
      for (int c = 16; c < 24; ++c) ACHUNK(c);
      WAITV(0);  SB0;                                                 // B3 in
      #pragma unroll
      for (int c = 24; c < 32; ++c) ACHUNK(c);
    }

    // ---- x part AFTER the GEMM (regs prefetched; zero load latency)
    {
      half8 xh0 = cvt8(xv0, xv1), xh1 = cvt8(xv2, xv3);
      half8 b0 = *(const half8*)(whp0 + 32 * 2048);
      half8 b1 = *(const half8*)(whp1 + 32 * 2048);
      P0 = MFMA16(b0, xh0, P0, 0, 0, 0);
      P1 = MFMA16(b1, xh0, P1, 0, 0, 0);
      b0 = *(const half8*)(whp0 + 33 * 2048);
      b1 = *(const half8*)(whp1 + 33 * 2048);
      P0 = MFMA16(b0, xh1, P0, 0, 0, 0);
      P1 = MFMA16(b1, xh1, P1, 0, 0, 0);
    }

    // ---- prefetch x/noise for t+1 (asm; latency hides under drain + poll)
    f32x4 y0, y1, y2, y3, m0, m1;
    {
      const int tt = (t + 1 < TT) ? t + 1 : t;   // clamp keeps vmcnt uniform
      const float* xp = xrow + (size_t)tt * NIN + g4 * 8;
      const float* np = noise + (size_t)tt * NRECN + cB;
      LDA16(y0, xp, 0);   LDA16(y1, xp, 16);
      LDA16(y2, xp, 128); LDA16(y3, xp, 144);
      LDA16(m0, np, 0);   LDA16(m1, np, 64);
    }

    // ---- epilogue: h, tanh, coalesced sc1 publish (r12 path)
    f32x4 h0, h1;
    #pragma unroll
    for (int r = 0; r < 4; ++r) {
      h0[r] = P0[r] + Q0[r] + nv0[r] * NOISE_STD;
      h1[r] = P1[r] + Q1[r] + nv1[r] * NOISE_STD;
    }
    _Float16* ob = thg + ((t + 1) & 1) * 8192;
    float tv0[4], tv1[4];
    #pragma unroll
    for (int r = 0; r < 4; ++r) {
      tv0[r] = 1.f - 2.f / (__expf(2.f * h0[r]) + 1.f);
      tv1[r] = 1.f - 2.f / (__expf(2.f * h1[r]) + 1.f);
    }
    if (l15 < 8) {
      u32x2 w0, w1;
      w0[0] = pk2h(tv0[0], tv0[1]); w0[1] = pk2h(tv0[2], tv0[3]);
      w1[0] = pk2h(tv1[0], tv1[1]); w1[1] = pk2h(tv1[2], tv1[3]);
      st_d2_sc1(ob + l15 * 1024 + cB, w0);
      st_d2_sc1(ob + l15 * 1024 + cB + 16, w1);
    }
    WAITV(0);          // publish (and prefetch) committed in every wave
    __syncthreads();   // join WG, then single post (r12 proven)
    if (tid == 0)
      __hip_atomic_fetch_add(ctr, 1, __ATOMIC_RELAXED,
                             __HIP_MEMORY_SCOPE_AGENT);

    // ---- rotate prefetched x/noise into current regs
    xv0 = y0; xv1 = y1; xv2 = y2; xv3 = y3; nv0 = m0; nv1 = m1;

    // ---- outputs, off the critical path (after post)
    if (grp == 7 && l15 == 7) {                  // batch 63 row
      #pragma unroll
      for (int r = 0; r < 4; ++r) {
        out[(size_t)(cB + r) * TT + t] = h0[r];
        out[(size_t)(cB + 16 + r) * TT + t] = h1[r];
      }
    }
    if (t == TT - 1 && l15 < 8) {                // final h, coalesced
      const int br = grp * 8 + l15;
      *(f32x4*)(out + (size_t)NRECN * TT + (size_t)br * NRECN + cB) = h0;
      *(f32x4*)(out + (size_t)NRECN * TT + (size_t)br * NRECN + cB + 16) = h1;
    }
  }
}

extern "C" void kernel_launch(void* const* d_in, const int* in_sizes, int n_in,
                              void* d_out, int out_size, void* d_ws, size_t ws_size,
                              hipStream_t stream) {
  const float* x     = (const float*)d_in[0];
  const float* W_ih  = (const float*)d_in[1];
  const float* W_hh  = (const float*)d_in[2];
  const float* noise = (const float*)d_in[3];
  float* out = (float*)d_out;

  char* ws = (char*)d_ws;
  int* flags = (int*)ws;                         // 8 counters, 64B apart
  _Float16* th = (_Float16*)(ws + 4096);         // [8][2][8][1024] f16 = 256 KB
  // ws usage: 4096 + 262144 = 266,240 bytes. Every tile byte is rewritten by
  // its group before being read -> no th memset needed.

  (void)hipMemsetAsync(flags, 0, 4096, stream);  // deterministic replays

  const size_t lds_bytes = (size_t)136 * 64 * 8 * sizeof(_Float16); // 139,264
  (void)hipFuncSetAttribute((const void*)rnn_scan_kernel,
                            hipFuncAttributeMaxDynamicSharedMemorySize,
                            (int)lds_bytes);

  rnn_scan_kernel<<<dim3(NWG), dim3(128), lds_bytes, stream>>>(
      x, W_ih, W_hh, noise, out, flags, th);
}